// Round 6
// baseline (2215.046 us; speedup 1.0000x reference)
//
#include <hip/hip_runtime.h>
#include <math.h>

typedef unsigned short u16;
typedef unsigned int   u32;
typedef __bf16  bf16x8 __attribute__((ext_vector_type(8)));
typedef float   f32x4  __attribute__((ext_vector_type(4)));
typedef u16     u16x8  __attribute__((ext_vector_type(8)));

__device__ __forceinline__ u16 f2bf(float f) {
  u32 u = __builtin_bit_cast(u32, f);
  u32 r = (u + 0x7fffu + ((u >> 16) & 1u)) >> 16;
  return (u16)r;
}
__device__ __forceinline__ float bf2f(u16 h) {
  u32 u = ((u32)h) << 16;
  return __builtin_bit_cast(float, u);
}
__device__ __forceinline__ void gload16(const void* g, void* l) {
  __builtin_amdgcn_global_load_lds((const __attribute__((address_space(1))) void*)g,
                                   (__attribute__((address_space(3))) void*)l, 16, 0, 0);
}
__device__ __forceinline__ bf16x8 ld_bf8(const u16* p) {
  u16x8 v = *(const u16x8*)p;
  return __builtin_bit_cast(bf16x8, v);
}
__device__ __forceinline__ f32x4 mfma16(bf16x8 a, bf16x8 b, f32x4 c) {
  return __builtin_amdgcn_mfma_f32_16x16x32_bf16(a, b, c, 0, 0, 0);
}

// ---------------------------------------------------------------- weights
struct ConvP {
  const float *wq, *wk, *wv, *wo, *wi, *wf;
  u16 *oqkv, *oo, *oi, *of;
};
// transpose+convert one layer's weights: f32 [K,N] -> bf16 [N,K]
__global__ __launch_bounds__(256) void conv_weights(ConvP p) {
  int t = blockIdx.x;
  const float* in; u16* out; int K, N, tn, tk;
  if (t < 1728) { int wh = t / 576, tt = t % 576;
    in = wh==0 ? p.wq : (wh==1 ? p.wk : p.wv);
    out = p.oqkv + (size_t)wh * 768 * 768;
    K = 768; N = 768; tn = tt % 24; tk = tt / 24;
  } else if (t < 2304) { int tt = t - 1728; in = p.wo; out = p.oo; K=768;  N=768;  tn=tt%24; tk=tt/24; }
  else if (t < 4608)   { int tt = t - 2304; in = p.wi; out = p.oi; K=768;  N=3072; tn=tt%96; tk=tt/96; }
  else                 { int tt = t - 4608; in = p.wf; out = p.of; K=3072; N=768;  tn=tt%24; tk=tt/24; }
  int n0 = tn*32, k0 = tk*32;
  __shared__ float tile[32][33];
  int x = threadIdx.x, y = threadIdx.y;
  #pragma unroll
  for (int j = 0; j < 4; ++j)
    tile[y + j*8][x] = in[(size_t)(k0 + y + j*8) * N + n0 + x];
  __syncthreads();
  #pragma unroll
  for (int j = 0; j < 4; ++j)
    out[(size_t)(n0 + y + j*8) * K + k0 + x] = f2bf(tile[x][y + j*8]);
}

// ---------------------------------------------------------------- GEMM (A[M,K] bf16 x B^T[N,K] bf16)
struct GP {
  const u16* A; const u16* B;
  int K, N;
  long sA, sB, sOut;
  const float* bias; const float* res;
  float* outF; u16* outB;
  const float* bq; const float* bk; const float* bv;
  u16* qO; u16* kO; u16* vO;
};

// WAVES=4 -> 2x2 wave grid, WAVES=8 -> 2x4. KS = K-split factor (EPI==2 only).
// EPI: 0=QKV scatter, 1=ctx scatter, 2=f32 partial, 3=gelu->bf16
template<int BM, int BN, int WAVES, int EPI, int KS>
__global__ __launch_bounds__(WAVES*64) void gemm_bt(GP p) {
  constexpr int THREADS = WAVES * 64;
  constexpr int WC = WAVES / 2;
  constexpr int WM = BM / 2, WN = BN / WC, MR = WM / 16, NR = WN / 16;
  constexpr int AIT = BM * 64 / (THREADS * 8);
  constexpr int BIT = BN * 64 / (THREADS * 8);
  const int tid = threadIdx.x;
  const int wave = tid >> 6, lane = tid & 63;
  const int wr = wave / WC, wc = wave % WC;
  const int wm0 = wr * WM, wn0 = wc * WN;
  const int bn = blockIdx.x, bm = blockIdx.y, bz = blockIdx.z;
  const int K = p.K;
  const int kLen = K / KS;
  const int kBeg = (KS > 1) ? bz * kLen : 0;
  const u16* A  = p.A + ((KS > 1) ? 0 : (size_t)bz * p.sA);
  const u16* Bp = p.B + ((KS > 1) ? 0 : (size_t)bz * p.sB);
  const int rowA0 = bm * BM, colB0 = bn * BN;

  __shared__ __align__(16) u16 lds[(BM + BN) * 64];
  u16* Al = lds; u16* Bl = lds + BM * 64;

  f32x4 acc[MR][NR];
  #pragma unroll
  for (int i = 0; i < MR; ++i)
    #pragma unroll
    for (int j = 0; j < NR; ++j) acc[i][j] = f32x4{0.f,0.f,0.f,0.f};

  for (int kt = kBeg; kt < kBeg + kLen; kt += 64) {
    #pragma unroll
    for (int it = 0; it < AIT; ++it) {
      int e = tid * 8 + it * THREADS * 8;
      gload16(A + (size_t)(rowA0 + (e >> 6)) * K + kt + (e & 63), Al + e);
    }
    #pragma unroll
    for (int it = 0; it < BIT; ++it) {
      int e = tid * 8 + it * THREADS * 8;
      gload16(Bp + (size_t)(colB0 + (e >> 6)) * K + kt + (e & 63), Bl + e);
    }
    __syncthreads();
    #pragma unroll
    for (int ks = 0; ks < 2; ++ks) {
      bf16x8 av[MR]; bf16x8 bw[NR];
      #pragma unroll
      for (int mf = 0; mf < MR; ++mf)
        av[mf] = ld_bf8(Al + (wm0 + mf*16 + (lane&15))*64 + ks*32 + (lane>>4)*8);
      #pragma unroll
      for (int nf = 0; nf < NR; ++nf)
        bw[nf] = ld_bf8(Bl + (wn0 + nf*16 + (lane&15))*64 + ks*32 + (lane>>4)*8);
      #pragma unroll
      for (int mf = 0; mf < MR; ++mf)
        #pragma unroll
        for (int nf = 0; nf < NR; ++nf)
          acc[mf][nf] = mfma16(av[mf], bw[nf], acc[mf][nf]);
    }
    __syncthreads();
  }

  #pragma unroll
  for (int mf = 0; mf < MR; ++mf) {
    #pragma unroll
    for (int nf = 0; nf < NR; ++nf) {
      int col = colB0 + wn0 + nf*16 + (lane & 15);
      #pragma unroll
      for (int reg = 0; reg < 4; ++reg) {
        int row = rowA0 + wm0 + mf*16 + (lane >> 4)*4 + reg;
        float v = acc[mf][nf][reg];
        if constexpr (EPI == 0) { // QKV scatter
          int wh = col / 768, cc = col % 768;
          int hh = cc >> 6, d = col & 63;
          int b = row >> 9, s = row & 511;
          const float* bias = wh==0 ? p.bq : (wh==1 ? p.bk : p.bv);
          u16 o = f2bf(v + bias[cc]);
          if (wh == 0)      p.qO[((((size_t)b*12 + hh)*512 + s) << 6) + d] = o;
          else if (wh == 1) p.kO[((((size_t)b*12 + hh)*512 + s) << 6) + d] = o;
          else              p.vO[((((size_t)b*12 + hh)*64  + d) << 9) + s] = o;
        } else if constexpr (EPI == 1) { // ctx scatter
          int b = bz / 12, hh = bz % 12;
          p.outB[((size_t)(b*512 + row))*768 + hh*64 + col] = f2bf(v);
        } else if constexpr (EPI == 2) { // raw f32 partial (bias/res folded into LN)
          p.outF[(size_t)bz * p.sOut + (size_t)row * p.N + col] = v;
        } else { // gelu -> bf16
          float xg = v + p.bias[col];
          float gg = 0.5f * xg * (1.f + erff(xg * 0.70710678118f));
          p.outB[(size_t)row * p.N + col] = f2bf(gg);
        }
      }
    }
  }
}

// ---------------------------------------------------------------- fused scores+softmax
// block: 64 q-rows x all 512 t for one head. grid (head=48, bm=8) -> same-head
// blocks land on one XCD (stride 48 = 0 mod 8). 4 waves, wave wc owns cols
// wc*128..+128. LDS-staged GEMM + block-internal softmax; probs -> global bf16.
template<int RAT>
__global__ __launch_bounds__(256) void scores_sm(
    const u16* __restrict__ q, const u16* __restrict__ k,
    const int* __restrict__ mask, u16* __restrict__ probs,
    const float* __restrict__ qr, const int* __restrict__ rel,
    float* __restrict__ wbins) {
  const int head = blockIdx.x;        // 0..47
  const int bm   = blockIdx.y;        // 0..7
  const int b = head / 12;
  const int row0 = bm * 64;
  const int tid = threadIdx.x, wc = tid >> 6, lane = tid & 63;

  __shared__ __align__(16) u16 lds[(64 + 512) * 64];    // Al 8KB + Bl 64KB
  u16* Al = lds;
  u16* Bl = lds + 64*64;
  __shared__ float em_lds[512];
  __shared__ float red[64][4];
  __shared__ float gmax[64], gsum[64];

  for (int i = tid; i < 512; i += 256)
    em_lds[i] = -10000.f * (1.f - (float)mask[b*512 + i]);

  const u16* qb = q + (size_t)head * 512 * 64;
  const u16* kb = k + (size_t)head * 512 * 64;
  #pragma unroll
  for (int it = 0; it < 2; ++it) {
    int e = tid*8 + it*2048;
    gload16(qb + (size_t)(row0 + (e>>6))*64 + (e&63), Al + e);
  }
  #pragma unroll
  for (int it = 0; it < 16; ++it) {
    int e = tid*8 + it*2048;
    gload16(kb + (size_t)(e>>6)*64 + (e&63), Bl + e);
  }
  __syncthreads();

  f32x4 acc[4][8];
  #pragma unroll
  for (int mf = 0; mf < 4; ++mf)
    #pragma unroll
    for (int nf = 0; nf < 8; ++nf) acc[mf][nf] = f32x4{0.f,0.f,0.f,0.f};

  #pragma unroll
  for (int ks = 0; ks < 2; ++ks) {
    bf16x8 av[4]; bf16x8 bw[8];
    #pragma unroll
    for (int mf = 0; mf < 4; ++mf)
      av[mf] = ld_bf8(Al + (mf*16 + (lane&15))*64 + ks*32 + (lane>>4)*8);
    #pragma unroll
    for (int nf = 0; nf < 8; ++nf)
      bw[nf] = ld_bf8(Bl + (wc*128 + nf*16 + (lane&15))*64 + ks*32 + (lane>>4)*8);
    #pragma unroll
    for (int mf = 0; mf < 4; ++mf)
      #pragma unroll
      for (int nf = 0; nf < 8; ++nf)
        acc[mf][nf] = mfma16(av[mf], bw[nf], acc[mf][nf]);
  }
  __syncthreads();   // MFMA done; Al/Bl dead from here (RAT aliases them)

  float* wlds = (float*)lds;                 // [64][52] (RAT only)
  float* qlds = (float*)(lds + 32768);       // [64][52] (RAT only)
  if constexpr (RAT) {
    for (int i = tid; i < 64*52; i += 256) wlds[i] = 0.f;
    for (int i = tid; i < 64*50; i += 256) {
      int rr = i % 50, sr = i / 50;
      qlds[sr*52 + rr] = qr[((size_t)head*512 + row0 + sr)*50 + rr];
    }
    __syncthreads();
    #pragma unroll
    for (int mf = 0; mf < 4; ++mf)
      #pragma unroll
      for (int nf = 0; nf < 8; ++nf) {
        int col = wc*128 + nf*16 + (lane&15);
        #pragma unroll
        for (int reg = 0; reg < 4; ++reg) {
          int row = mf*16 + (lane>>4)*4 + reg;
          int rr = rel[((size_t)(b*512 + row0 + row))*512 + col];
          acc[mf][nf][reg] += qlds[row*52 + rr];
        }
      }
  }

  // scale + mask
  #pragma unroll
  for (int mf = 0; mf < 4; ++mf)
    #pragma unroll
    for (int nf = 0; nf < 8; ++nf) {
      float em = em_lds[wc*128 + nf*16 + (lane&15)];
      #pragma unroll
      for (int reg = 0; reg < 4; ++reg)
        acc[mf][nf][reg] = acc[mf][nf][reg] * 0.125f + em;
    }

  // row max over this wave's 128 cols, then cross-wave via LDS
  #pragma unroll
  for (int mf = 0; mf < 4; ++mf)
    #pragma unroll
    for (int reg = 0; reg < 4; ++reg) {
      int row = mf*16 + (lane>>4)*4 + reg;
      float m = acc[mf][0][reg];
      #pragma unroll
      for (int nf = 1; nf < 8; ++nf) m = fmaxf(m, acc[mf][nf][reg]);
      #pragma unroll
      for (int o = 1; o < 16; o <<= 1) m = fmaxf(m, __shfl_xor(m, o));
      if ((lane & 15) == 0) red[row][wc] = m;
    }
  __syncthreads();
  if (tid < 64)
    gmax[tid] = fmaxf(fmaxf(red[tid][0], red[tid][1]), fmaxf(red[tid][2], red[tid][3]));
  __syncthreads();

  // exp + row sum
  #pragma unroll
  for (int mf = 0; mf < 4; ++mf)
    #pragma unroll
    for (int reg = 0; reg < 4; ++reg) {
      int row = mf*16 + (lane>>4)*4 + reg;
      float gm = gmax[row];
      float s = 0.f;
      #pragma unroll
      for (int nf = 0; nf < 8; ++nf) {
        float e = __expf(acc[mf][nf][reg] - gm);
        acc[mf][nf][reg] = e;
        s += e;
      }
      #pragma unroll
      for (int o = 1; o < 16; o <<= 1) s += __shfl_xor(s, o);
      if ((lane & 15) == 0) red[row][wc] = s;
    }
  __syncthreads();
  if (tid < 64)
    gsum[tid] = red[tid][0] + red[tid][1] + red[tid][2] + red[tid][3];
  __syncthreads();

  // normalize + store probs (+ RAT bins)
  #pragma unroll
  for (int mf = 0; mf < 4; ++mf)
    #pragma unroll
    for (int reg = 0; reg < 4; ++reg) {
      int row = mf*16 + (lane>>4)*4 + reg;
      float inv = 1.f / gsum[row];
      size_t rowbase = ((size_t)head*512 + row0 + row) * 512;
      #pragma unroll
      for (int nf = 0; nf < 8; ++nf) {
        int col = wc*128 + nf*16 + (lane&15);
        float pval = acc[mf][nf][reg] * inv;
        probs[rowbase + col] = f2bf(pval);
        if constexpr (RAT) {
          int rr = rel[((size_t)(b*512 + row0 + row))*512 + col];
          atomicAdd(&wlds[row*52 + rr], pval);
        }
      }
    }
  if constexpr (RAT) {
    __syncthreads();
    for (int i = tid; i < 64*50; i += 256) {
      int rr = i % 50, sr = i / 50;
      wbins[((size_t)head*512 + row0 + sr)*50 + rr] = wlds[sr*52 + rr];
    }
  }
}

// ---------------------------------------------------------------- RAT helpers (layer 6)
__global__ __launch_bounds__(256) void rat_qr(const u16* __restrict__ q,
    const float* __restrict__ kr, float* __restrict__ qr) {
  int idx = blockIdx.x * 256 + threadIdx.x;
  if (idx >= 24576 * 50) return;
  int r = idx % 50; size_t bhs = (size_t)idx / 50;
  const u16* qp = q + bhs * 64;
  const float* kp = kr + r * 64;
  float acc = 0.f;
  #pragma unroll
  for (int d = 0; d < 64; ++d) acc += bf2f(qp[d]) * kp[d];
  qr[idx] = acc;
}

// ctx[bhs, d] += sum_r wbins[bhs, r] * vr[r, d]
__global__ __launch_bounds__(256) void rat_apply(const float* __restrict__ wbins,
    const float* __restrict__ vr, u16* __restrict__ ctx) {
  __shared__ float vrl[50*64];
  __shared__ float wl[32*50];
  int tid = threadIdx.x;
  int rows0 = blockIdx.x * 32;
  for (int i = tid; i < 50*64; i += 256) vrl[i] = vr[i];
  for (int i = tid; i < 32*50; i += 256) wl[i] = wbins[(size_t)rows0*50 + i];
  __syncthreads();
  int wave = tid >> 6, lane = tid & 63;
  #pragma unroll
  for (int i = 0; i < 8; ++i) {
    int r = wave*8 + i;
    size_t idx = (size_t)rows0 + r;
    float acc = 0.f;
    #pragma unroll
    for (int j = 0; j < 50; ++j) acc += wl[r*50 + j] * vrl[j*64 + lane];
    int s = (int)(idx & 511); size_t bh = idx >> 9;
    int b = (int)(bh / 12), hh = (int)(bh % 12);
    u16* cp = ctx + ((size_t)(b*512 + s))*768 + hh*64 + lane;
    *cp = f2bf(bf2f(*cp) + acc);
  }
}

// ---------------------------------------------------------------- embeddings + LN
__global__ __launch_bounds__(256) void embed_ln(const int* __restrict__ ids,
    const float* __restrict__ we, const float* __restrict__ pe, const float* __restrict__ te,
    const float* __restrict__ g, const float* __restrict__ b,
    float* __restrict__ hF, u16* __restrict__ hB) {
  int row = blockIdx.x, tid = threadIdx.x;
  int s = row & 511;
  int id = ids[row];
  float x[3];
  #pragma unroll
  for (int j = 0; j < 3; ++j) {
    int d = tid + j*256;
    x[j] = we[(size_t)id*768 + d] + pe[(size_t)s*768 + d] + te[d];
  }
  __shared__ float red[4];
  float sm = x[0] + x[1] + x[2];
  #pragma unroll
  for (int o = 32; o; o >>= 1) sm += __shfl_xor(sm, o);
  if (!(tid & 63)) red[tid >> 6] = sm;
  __syncthreads();
  float mean = (red[0]+red[1]+red[2]+red[3]) * (1.f/768.f);
  __syncthreads();
  float q = 0.f;
  #pragma unroll
  for (int j = 0; j < 3; ++j) { float d = x[j] - mean; q += d*d; }
  #pragma unroll
  for (int o = 32; o; o >>= 1) q += __shfl_xor(q, o);
  if (!(tid & 63)) red[tid >> 6] = q;
  __syncthreads();
  float inv = rsqrtf((red[0]+red[1]+red[2]+red[3]) * (1.f/768.f) + 1e-12f);
  #pragma unroll
  for (int j = 0; j < 3; ++j) {
    int d = tid + j*256;
    float y = (x[j] - mean) * inv * g[d] + b[d];
    hF[(size_t)row*768 + d] = y;
    hB[(size_t)row*768 + d] = f2bf(y);
  }
}

// LN over (p0[+p1][+p2][+p3]) + bias + res
__global__ __launch_bounds__(256) void ln_fused(const float* __restrict__ p0,
    const float* __restrict__ p1, const float* __restrict__ p2, const float* __restrict__ p3,
    int np, const float* __restrict__ bias, const float* __restrict__ res,
    const float* __restrict__ g, const float* __restrict__ b,
    float* __restrict__ oF, u16* __restrict__ oB) {
  int row = blockIdx.x, tid = threadIdx.x;
  size_t base = (size_t)row * 768;
  float v[3];
  #pragma unroll
  for (int j = 0; j < 3; ++j) {
    int d = tid + j*256;
    float x = p0[base + d];
    if (np > 1) x += p1[base + d];
    if (np > 2) x += p2[base + d];
    if (np > 3) x += p3[base + d];
    v[j] = x + bias[d] + res[base + d];
  }
  __shared__ float red[4];
  float sm = v[0] + v[1] + v[2];
  #pragma unroll
  for (int o = 32; o; o >>= 1) sm += __shfl_xor(sm, o);
  if (!(tid & 63)) red[tid >> 6] = sm;
  __syncthreads();
  float mean = (red[0]+red[1]+red[2]+red[3]) * (1.f/768.f);
  __syncthreads();
  float q = 0.f;
  #pragma unroll
  for (int j = 0; j < 3; ++j) { float d = v[j] - mean; q += d*d; }
  #pragma unroll
  for (int o = 32; o; o >>= 1) q += __shfl_xor(q, o);
  if (!(tid & 63)) red[tid >> 6] = q;
  __syncthreads();
  float inv = rsqrtf((red[0]+red[1]+red[2]+red[3]) * (1.f/768.f) + 1e-12f);
  #pragma unroll
  for (int j = 0; j < 3; ++j) {
    int d = tid + j*256;
    float y = (v[j] - mean) * inv * g[d] + b[d];
    oF[base + d] = y;
    oB[base + d] = f2bf(y);
  }
}

// ---------------------------------------------------------------- tail
__global__ __launch_bounds__(256) void pooler_k(const float* __restrict__ h,
    const float* __restrict__ w, const float* __restrict__ bias, float* __restrict__ out) {
  int b = blockIdx.x, tid = threadIdx.x;
  __shared__ float hr[768];
  for (int i = tid; i < 768; i += 256) hr[i] = h[((size_t)b*512)*768 + i];
  __syncthreads();
  float a0 = 0.f, a1 = 0.f, a2 = 0.f;
  for (int kk = 0; kk < 768; ++kk) {
    float hv = hr[kk];
    const float* wr = w + (size_t)kk*768;
    a0 += hv * wr[tid]; a1 += hv * wr[tid+256]; a2 += hv * wr[tid+512];
  }
  out[(size_t)b*768 + tid]       = tanhf(a0 + bias[tid]);
  out[(size_t)b*768 + tid + 256] = tanhf(a1 + bias[tid+256]);
  out[(size_t)b*768 + tid + 512] = tanhf(a2 + bias[tid+512]);
}

__global__ __launch_bounds__(256) void copy_out(const float* __restrict__ in, float* __restrict__ out) {
  size_t i = ((size_t)blockIdx.x * 256 + threadIdx.x) * 4;
  *(float4*)(out + i) = *(const float4*)(in + i);
}

// ---------------------------------------------------------------- host
extern "C" void kernel_launch(void* const* d_in, const int* in_sizes, int n_in,
                              void* d_out, int out_size, void* d_ws, size_t ws_size,
                              hipStream_t stream) {
  const int*   ids   = (const int*)d_in[0];
  const int*   rel   = (const int*)d_in[1];
  const int*   amask = (const int*)d_in[2];
  const float* we    = (const float*)d_in[3];
  const float* pe    = (const float*)d_in[4];
  const float* te    = (const float*)d_in[5];
  const float* eg    = (const float*)d_in[6];
  const float* ebb   = (const float*)d_in[7];
  const float* Wq    = (const float*)d_in[8];
  const float* bq    = (const float*)d_in[9];
  const float* Wk    = (const float*)d_in[10];
  const float* bk    = (const float*)d_in[11];
  const float* Wv    = (const float*)d_in[12];
  const float* bv    = (const float*)d_in[13];
  const float* Wo    = (const float*)d_in[14];
  const float* bo    = (const float*)d_in[15];
  const float* g1    = (const float*)d_in[16];
  const float* b1    = (const float*)d_in[17];
  const float* Wi    = (const float*)d_in[18];
  const float* bi    = (const float*)d_in[19];
  const float* Wf    = (const float*)d_in[20];
  const float* bfp   = (const float*)d_in[21];
  const float* g2    = (const float*)d_in[22];
  const float* b2    = (const float*)d_in[23];
  const float* krel  = (const float*)d_in[24];
  const float* vrel  = (const float*)d_in[25];
  const float* pwp   = (const float*)d_in[26];
  const float* pbp   = (const float*)d_in[27];
  (void)in_sizes; (void)n_in; (void)out_size; (void)ws_size;

  char* ws = (char*)d_ws;
  size_t off = 0;
  auto take = [&](size_t bytes) { char* p = ws + off; off += (bytes + 255) & ~(size_t)255; return p; };
  u16*   wqkv = (u16*)take((size_t)2304*768*2);
  u16*   wo_l = (u16*)take((size_t)768*768*2);
  u16*   wi_l = (u16*)take((size_t)3072*768*2);
  u16*   wf_l = (u16*)take((size_t)768*3072*2);
  float* hF   = (float*)take((size_t)2048*768*4);
  u16*   hB   = (u16*)take((size_t)2048*768*2);
  float* atF  = (float*)take((size_t)2048*768*4);
  u16*   atB  = (u16*)take((size_t)2048*768*2);
  u16*   qB   = (u16*)take((size_t)2048*768*2);
  u16*   kB   = (u16*)take((size_t)2048*768*2);
  u16*   vB   = (u16*)take((size_t)2048*768*2);
  u16*   ctxB = (u16*)take((size_t)2048*768*2);
  float* tmpF = (float*)take((size_t)4*2048*768*4);   // 4 split-K partials
  u16*   ffB  = (u16*)take((size_t)2048*3072*2);
  u16*   prB  = (u16*)take((size_t)48*512*512*2);     // probs bf16
  float* qrF  = (float*)take((size_t)24576*50*4);
  float* wbF  = (float*)take((size_t)24576*50*4);
  const size_t PSTRIDE = (size_t)2048*768;

  embed_ln<<<2048, 256, 0, stream>>>(ids, we, pe, te, eg, ebb, hF, hB);

  for (int l = 0; l < 12; ++l) {
    ConvP cp{Wq + (size_t)l*768*768, Wk + (size_t)l*768*768, Wv + (size_t)l*768*768,
             Wo + (size_t)l*768*768, Wi + (size_t)l*768*3072, Wf + (size_t)l*3072*768,
             wqkv, wo_l, wi_l, wf_l};
    conv_weights<<<6912, dim3(32,8), 0, stream>>>(cp);

    GP pq{}; pq.A = hB; pq.B = wqkv; pq.K = 768; pq.N = 2304;
    pq.bq = bq + l*768; pq.bk = bk + l*768; pq.bv = bv + l*768;
    pq.qO = qB; pq.kO = kB; pq.vO = vB;
    gemm_bt<128,128,8,0,1><<<dim3(18,16,1), 512, 0, stream>>>(pq);

    if (l == 6) {
      rat_qr<<<4800, 256, 0, stream>>>(qB, krel + 6*50*64, qrF);
      scores_sm<1><<<dim3(48,8), 256, 0, stream>>>(qB, kB, amask, prB, qrF, rel, wbF);
    } else {
      scores_sm<0><<<dim3(48,8), 256, 0, stream>>>(qB, kB, amask, prB, qrF, rel, wbF);
    }

    // ctx = probs @ V (batched)
    GP pc{}; pc.A = prB; pc.B = vB; pc.K = 512; pc.N = 64;
    pc.sA = (long)512*512; pc.sB = 64*512; pc.outB = ctxB;
    gemm_bt<64,64,4,1,1><<<dim3(1,8,48), 256, 0, stream>>>(pc);
    if (l == 6) rat_apply<<<768, 256, 0, stream>>>(wbF, vrel + 6*50*64, ctxB);

    GP po{}; po.A = ctxB; po.B = wo_l; po.K = 768; po.N = 768; po.sOut = PSTRIDE;
    po.outF = tmpF;
    gemm_bt<64,128,4,2,2><<<dim3(6,32,2), 256, 0, stream>>>(po);
    ln_fused<<<2048, 256, 0, stream>>>(tmpF, tmpF + PSTRIDE, nullptr, nullptr, 2,
                                       bo + l*768, hF, g1 + l*768, b1 + l*768, atF, atB);

    GP pf1{}; pf1.A = atB; pf1.B = wi_l; pf1.K = 768; pf1.N = 3072;
    pf1.bias = bi + (size_t)l*3072; pf1.outB = ffB;
    gemm_bt<128,128,8,3,1><<<dim3(24,16,1), 512, 0, stream>>>(pf1);

    GP pf2{}; pf2.A = ffB; pf2.B = wf_l; pf2.K = 3072; pf2.N = 768; pf2.sOut = PSTRIDE;
    pf2.outF = tmpF;
    gemm_bt<64,128,4,2,4><<<dim3(6,32,4), 256, 0, stream>>>(pf2);
    ln_fused<<<2048, 256, 0, stream>>>(tmpF, tmpF + PSTRIDE, tmpF + 2*PSTRIDE, tmpF + 3*PSTRIDE, 4,
                                       bfp + l*768, atF, g2 + l*768, b2 + l*768, hF, hB);
  }

  copy_out<<<1536, 256, 0, stream>>>(hF, (float*)d_out);
  pooler_k<<<4, 256, 0, stream>>>(hF, pwp, pbp, (float*)d_out + (size_t)2048*768);
}

// Round 7
// 1914.466 us; speedup vs baseline: 1.1570x; 1.1570x over previous
//
#include <hip/hip_runtime.h>
#include <math.h>

typedef unsigned short u16;
typedef unsigned int   u32;
typedef __bf16  bf16x8 __attribute__((ext_vector_type(8)));
typedef float   f32x4  __attribute__((ext_vector_type(4)));
typedef u16     u16x8  __attribute__((ext_vector_type(8)));

__device__ __forceinline__ u16 f2bf(float f) {
  u32 u = __builtin_bit_cast(u32, f);
  u32 r = (u + 0x7fffu + ((u >> 16) & 1u)) >> 16;
  return (u16)r;
}
__device__ __forceinline__ float bf2f(u16 h) {
  u32 u = ((u32)h) << 16;
  return __builtin_bit_cast(float, u);
}
__device__ __forceinline__ void gload16(const void* g, void* l) {
  __builtin_amdgcn_global_load_lds((const __attribute__((address_space(1))) void*)g,
                                   (__attribute__((address_space(3))) void*)l, 16, 0, 0);
}
__device__ __forceinline__ bf16x8 ld_bf8(const u16* p) {
  u16x8 v = *(const u16x8*)p;
  return __builtin_bit_cast(bf16x8, v);
}
__device__ __forceinline__ f32x4 mfma16(bf16x8 a, bf16x8 b, f32x4 c) {
  return __builtin_amdgcn_mfma_f32_16x16x32_bf16(a, b, c, 0, 0, 0);
}

// ---------------------------------------------------------------- weights
struct ConvP {
  const float *wq, *wk, *wv, *wo, *wi, *wf;
  u16 *oqkv, *oo, *oi, *of;
};
// transpose+convert one layer's weights: f32 [K,N] -> bf16 [N,K]
__global__ __launch_bounds__(256) void conv_weights(ConvP p) {
  int t = blockIdx.x;
  const float* in; u16* out; int K, N, tn, tk;
  if (t < 1728) { int wh = t / 576, tt = t % 576;
    in = wh==0 ? p.wq : (wh==1 ? p.wk : p.wv);
    out = p.oqkv + (size_t)wh * 768 * 768;
    K = 768; N = 768; tn = tt % 24; tk = tt / 24;
  } else if (t < 2304) { int tt = t - 1728; in = p.wo; out = p.oo; K=768;  N=768;  tn=tt%24; tk=tt/24; }
  else if (t < 4608)   { int tt = t - 2304; in = p.wi; out = p.oi; K=768;  N=3072; tn=tt%96; tk=tt/96; }
  else                 { int tt = t - 4608; in = p.wf; out = p.of; K=3072; N=768;  tn=tt%24; tk=tt/24; }
  int n0 = tn*32, k0 = tk*32;
  __shared__ float tile[32][33];
  int x = threadIdx.x, y = threadIdx.y;
  #pragma unroll
  for (int j = 0; j < 4; ++j)
    tile[y + j*8][x] = in[(size_t)(k0 + y + j*8) * N + n0 + x];
  __syncthreads();
  #pragma unroll
  for (int j = 0; j < 4; ++j)
    out[(size_t)(n0 + y + j*8) * K + k0 + x] = f2bf(tile[x][y + j*8]);
}

// ---------------------------------------------------------------- GEMM (A[M,K] bf16 x B^T[N,K] bf16)
struct GP {
  const u16* A; const u16* B;
  int K, N;
  long sA, sB, sOut;
  const float* bias; const float* res;
  float* outF; u16* outB;
  const float* bq; const float* bk; const float* bv;
  u16* qO; u16* kO; u16* vO;
};

// WAVES=4 -> 2x2 wave grid, WAVES=8 -> 2x4. KS = K-split factor (EPI==2 only).
// EPI: 0=QKV scatter, 1=ctx scatter, 2=f32 partial, 3=gelu->bf16, 4=raw bf16 (scores)
template<int BM, int BN, int WAVES, int EPI, int KS>
__global__ __launch_bounds__(WAVES*64) void gemm_bt(GP p) {
  constexpr int THREADS = WAVES * 64;
  constexpr int WC = WAVES / 2;
  constexpr int WM = BM / 2, WN = BN / WC, MR = WM / 16, NR = WN / 16;
  constexpr int AIT = BM * 64 / (THREADS * 8);
  constexpr int BIT = BN * 64 / (THREADS * 8);
  const int tid = threadIdx.x;
  const int wave = tid >> 6, lane = tid & 63;
  const int wr = wave / WC, wc = wave % WC;
  const int wm0 = wr * WM, wn0 = wc * WN;
  const int bn = blockIdx.x, bm = blockIdx.y, bz = blockIdx.z;
  const int K = p.K;
  const int kLen = K / KS;
  const int kBeg = (KS > 1) ? bz * kLen : 0;
  const u16* A  = p.A + ((KS > 1) ? 0 : (size_t)bz * p.sA);
  const u16* Bp = p.B + ((KS > 1) ? 0 : (size_t)bz * p.sB);
  const int rowA0 = bm * BM, colB0 = bn * BN;

  __shared__ __align__(16) u16 lds[(BM + BN) * 64];
  u16* Al = lds; u16* Bl = lds + BM * 64;

  f32x4 acc[MR][NR];
  #pragma unroll
  for (int i = 0; i < MR; ++i)
    #pragma unroll
    for (int j = 0; j < NR; ++j) acc[i][j] = f32x4{0.f,0.f,0.f,0.f};

  for (int kt = kBeg; kt < kBeg + kLen; kt += 64) {
    #pragma unroll
    for (int it = 0; it < AIT; ++it) {
      int e = tid * 8 + it * THREADS * 8;
      gload16(A + (size_t)(rowA0 + (e >> 6)) * K + kt + (e & 63), Al + e);
    }
    #pragma unroll
    for (int it = 0; it < BIT; ++it) {
      int e = tid * 8 + it * THREADS * 8;
      gload16(Bp + (size_t)(colB0 + (e >> 6)) * K + kt + (e & 63), Bl + e);
    }
    __syncthreads();
    #pragma unroll
    for (int ks = 0; ks < 2; ++ks) {
      bf16x8 av[MR]; bf16x8 bw[NR];
      #pragma unroll
      for (int mf = 0; mf < MR; ++mf)
        av[mf] = ld_bf8(Al + (wm0 + mf*16 + (lane&15))*64 + ks*32 + (lane>>4)*8);
      #pragma unroll
      for (int nf = 0; nf < NR; ++nf)
        bw[nf] = ld_bf8(Bl + (wn0 + nf*16 + (lane&15))*64 + ks*32 + (lane>>4)*8);
      #pragma unroll
      for (int mf = 0; mf < MR; ++mf)
        #pragma unroll
        for (int nf = 0; nf < NR; ++nf)
          acc[mf][nf] = mfma16(av[mf], bw[nf], acc[mf][nf]);
    }
    __syncthreads();
  }

  #pragma unroll
  for (int mf = 0; mf < MR; ++mf) {
    #pragma unroll
    for (int nf = 0; nf < NR; ++nf) {
      int col = colB0 + wn0 + nf*16 + (lane & 15);
      #pragma unroll
      for (int reg = 0; reg < 4; ++reg) {
        int row = rowA0 + wm0 + mf*16 + (lane >> 4)*4 + reg;
        float v = acc[mf][nf][reg];
        if constexpr (EPI == 0) { // QKV scatter
          int wh = col / 768, cc = col % 768;
          int hh = cc >> 6, d = col & 63;
          int b = row >> 9, s = row & 511;
          const float* bias = wh==0 ? p.bq : (wh==1 ? p.bk : p.bv);
          u16 o = f2bf(v + bias[cc]);
          if (wh == 0)      p.qO[((((size_t)b*12 + hh)*512 + s) << 6) + d] = o;
          else if (wh == 1) p.kO[((((size_t)b*12 + hh)*512 + s) << 6) + d] = o;
          else              p.vO[((((size_t)b*12 + hh)*64  + d) << 9) + s] = o;
        } else if constexpr (EPI == 1) { // ctx scatter
          int b = bz / 12, hh = bz % 12;
          p.outB[((size_t)(b*512 + row))*768 + hh*64 + col] = f2bf(v);
        } else if constexpr (EPI == 2) { // raw f32 partial (bias/res folded into LN)
          p.outF[(size_t)bz * p.sOut + (size_t)row * p.N + col] = v;
        } else if constexpr (EPI == 3) { // gelu -> bf16
          float xg = v + p.bias[col];
          float gg = 0.5f * xg * (1.f + erff(xg * 0.70710678118f));
          p.outB[(size_t)row * p.N + col] = f2bf(gg);
        } else { // EPI == 4: raw bf16 (scores)
          p.outB[(size_t)bz * p.sOut + (size_t)row * p.N + col] = f2bf(v);
        }
      }
    }
  }
}

// ---------------------------------------------------------------- flash attention (non-RAT layers)
// block: 64 q-rows of one head, 4 waves (16 q-rows each). Loop 8 KV-tiles of 64:
// stage K/V^T tile in LDS (gload16), QK^T MFMA, online softmax in-register,
// P bounce through wave-private LDS (no barrier), PV MFMA with rescale.
__global__ __launch_bounds__(256) void flash_attn(
    const u16* __restrict__ q, const u16* __restrict__ k, const u16* __restrict__ v,
    const int* __restrict__ mask, u16* __restrict__ ctx) {
  const int head = blockIdx.x;   // 0..47
  const int bm = blockIdx.y;     // 0..7
  const int b = head / 12, hh = head % 12;
  const int tid = threadIdx.x, wave = tid >> 6, lane = tid & 63;
  const int row0 = bm * 64;
  const u16* qb = q + (size_t)head * 512 * 64;
  const u16* kb = k + (size_t)head * 512 * 64;
  const u16* vb = v + (size_t)head * 64 * 512;   // [d][t]

  __shared__ __align__(16) u16 Ql[64*64];
  __shared__ __align__(16) u16 Kl[64*64];
  __shared__ __align__(16) u16 Vl[64*64];
  __shared__ __align__(16) u16 pw[4][16*72];     // wave-private P tiles (pad 72)
  __shared__ float em_lds[512];

  for (int i = tid; i < 512; i += 256)
    em_lds[i] = -10000.f * (1.f - (float)mask[b*512 + i]);

  #pragma unroll
  for (int it = 0; it < 2; ++it) {
    int e = tid*8 + it*2048;
    gload16(qb + (size_t)(row0 + (e>>6))*64 + (e&63), Ql + e);
  }
  __syncthreads();
  bf16x8 qf[2];
  #pragma unroll
  for (int ks = 0; ks < 2; ++ks)
    qf[ks] = ld_bf8(Ql + (wave*16 + (lane&15))*64 + ks*32 + (lane>>4)*8);

  f32x4 ctxacc[4];
  #pragma unroll
  for (int nf = 0; nf < 4; ++nf) ctxacc[nf] = f32x4{0.f,0.f,0.f,0.f};
  float mrun[4], lrun[4];
  #pragma unroll
  for (int r = 0; r < 4; ++r) { mrun[r] = -3.0e38f; lrun[r] = 0.f; }

  for (int t0 = 0; t0 < 512; t0 += 64) {
    __syncthreads();   // previous tile fully consumed before overwrite
    #pragma unroll
    for (int it = 0; it < 2; ++it) {
      int e = tid*8 + it*2048;
      gload16(kb + (size_t)(t0 + (e>>6))*64 + (e&63), Kl + e);
    }
    #pragma unroll
    for (int it = 0; it < 2; ++it) {
      int e = tid*8 + it*2048;   // e>>6 = d, e&63 = t-local
      gload16(vb + (size_t)(e>>6)*512 + t0 + (e&63), Vl + e);
    }
    __syncthreads();

    // S = Q K^T (16 q-rows x 64 t per wave)
    f32x4 s[4];
    #pragma unroll
    for (int nf = 0; nf < 4; ++nf) s[nf] = f32x4{0.f,0.f,0.f,0.f};
    #pragma unroll
    for (int ks = 0; ks < 2; ++ks)
      #pragma unroll
      for (int nf = 0; nf < 4; ++nf) {
        bf16x8 kf = ld_bf8(Kl + (nf*16 + (lane&15))*64 + ks*32 + (lane>>4)*8);
        s[nf] = mfma16(qf[ks], kf, s[nf]);
      }

    float em4[4];
    #pragma unroll
    for (int nf = 0; nf < 4; ++nf) em4[nf] = em_lds[t0 + nf*16 + (lane&15)];

    float scale_[4];
    #pragma unroll
    for (int reg = 0; reg < 4; ++reg) {
      float pm = -3.0e38f;
      #pragma unroll
      for (int nf = 0; nf < 4; ++nf) {
        s[nf][reg] = s[nf][reg]*0.125f + em4[nf];
        pm = fmaxf(pm, s[nf][reg]);
      }
      #pragma unroll
      for (int o = 1; o < 16; o <<= 1) pm = fmaxf(pm, __shfl_xor(pm, o));
      float mnew = fmaxf(mrun[reg], pm);
      float sc = __expf(mrun[reg] - mnew);
      mrun[reg] = mnew;
      scale_[reg] = sc;
      float lsum = 0.f;
      #pragma unroll
      for (int nf = 0; nf < 4; ++nf) {
        float e = __expf(s[nf][reg] - mnew);
        s[nf][reg] = e;
        lsum += e;
      }
      #pragma unroll
      for (int o = 1; o < 16; o <<= 1) lsum += __shfl_xor(lsum, o);
      lrun[reg] = lrun[reg]*sc + lsum;
    }

    // P -> wave-private LDS (no barrier needed; DS ops in-order per wave)
    #pragma unroll
    for (int nf = 0; nf < 4; ++nf)
      #pragma unroll
      for (int reg = 0; reg < 4; ++reg) {
        int qq = (lane>>4)*4 + reg;
        pw[wave][qq*72 + nf*16 + (lane&15)] = f2bf(s[nf][reg]);
      }

    // rescale ctx, then PV accumulate
    #pragma unroll
    for (int nf = 0; nf < 4; ++nf)
      #pragma unroll
      for (int reg = 0; reg < 4; ++reg)
        ctxacc[nf][reg] *= scale_[reg];
    #pragma unroll
    for (int ks = 0; ks < 2; ++ks) {
      bf16x8 pf = ld_bf8(pw[wave] + (lane&15)*72 + ks*32 + (lane>>4)*8);
      #pragma unroll
      for (int nf = 0; nf < 4; ++nf) {
        bf16x8 vf = ld_bf8(Vl + (nf*16 + (lane&15))*64 + ks*32 + (lane>>4)*8);
        ctxacc[nf] = mfma16(pf, vf, ctxacc[nf]);
      }
    }
  }

  #pragma unroll
  for (int nf = 0; nf < 4; ++nf)
    #pragma unroll
    for (int reg = 0; reg < 4; ++reg) {
      int qg = row0 + wave*16 + (lane>>4)*4 + reg;
      int d  = nf*16 + (lane&15);
      ctx[((size_t)(b*512 + qg))*768 + hh*64 + d] = f2bf(ctxacc[nf][reg] / lrun[reg]);
    }
}

// ---------------------------------------------------------------- row softmax (+ RAT) — layer 6 only
template<int RAT>
__global__ __launch_bounds__(256) void softmax_k(
    const u16* __restrict__ sc, const int* __restrict__ mask,
    u16* __restrict__ probs, const float* __restrict__ qr,
    const int* __restrict__ rel, float* __restrict__ wbins) {
  const int wave = threadIdx.x >> 6, lane = threadIdx.x & 63;
  const int row = blockIdx.x * 4 + wave;       // head*512 + s
  const int head = row >> 9, s = row & 511;
  const int b = head / 12;

  __shared__ float qlds[4][52];
  __shared__ float wlds[4][52];
  if constexpr (RAT) {
    if (lane < 52) {
      qlds[wave][lane] = (lane < 50) ? qr[(size_t)row*50 + lane] : 0.f;
      wlds[wave][lane] = 0.f;
    }
  }
  __syncthreads();

  u16x8 sv = *(const u16x8*)(sc + (size_t)row*512 + lane*8);
  const int* relrow = rel + ((size_t)(b*512 + s))*512 + lane*8;
  const int* mrow   = mask + b*512 + lane*8;

  float x[8];
  int rr[8];
  #pragma unroll
  for (int j = 0; j < 8; ++j) {
    float v = bf2f(sv[j]);
    if constexpr (RAT) { rr[j] = relrow[j]; v += qlds[wave][rr[j]]; }
    x[j] = v * 0.125f + -10000.f * (1.f - (float)mrow[j]);
  }

  float m = x[0];
  #pragma unroll
  for (int j = 1; j < 8; ++j) m = fmaxf(m, x[j]);
  #pragma unroll
  for (int o = 1; o < 64; o <<= 1) m = fmaxf(m, __shfl_xor(m, o));

  float sum = 0.f;
  #pragma unroll
  for (int j = 0; j < 8; ++j) { x[j] = __expf(x[j] - m); sum += x[j]; }
  #pragma unroll
  for (int o = 1; o < 64; o <<= 1) sum += __shfl_xor(sum, o);
  float inv = 1.f / sum;

  u16x8 ov;
  #pragma unroll
  for (int j = 0; j < 8; ++j) {
    float pv = x[j] * inv;
    ov[j] = f2bf(pv);
    if constexpr (RAT) atomicAdd(&wlds[wave][rr[j]], pv);
  }
  *(u16x8*)(probs + (size_t)row*512 + lane*8) = ov;

  if constexpr (RAT) {
    __syncthreads();
    if (lane < 50) wbins[(size_t)row*50 + lane] = wlds[wave][lane];
  }
}

// ---------------------------------------------------------------- RAT helpers (layer 6)
__global__ __launch_bounds__(256) void rat_qr(const u16* __restrict__ q,
    const float* __restrict__ kr, float* __restrict__ qr) {
  int idx = blockIdx.x * 256 + threadIdx.x;
  if (idx >= 24576 * 50) return;
  int r = idx % 50; size_t bhs = (size_t)idx / 50;
  const u16* qp = q + bhs * 64;
  const float* kp = kr + r * 64;
  float acc = 0.f;
  #pragma unroll
  for (int d = 0; d < 64; ++d) acc += bf2f(qp[d]) * kp[d];
  qr[idx] = acc;
}

__global__ __launch_bounds__(256) void rat_apply(const float* __restrict__ wbins,
    const float* __restrict__ vr, u16* __restrict__ ctx) {
  __shared__ float vrl[50*64];
  __shared__ float wl[32*50];
  int tid = threadIdx.x;
  int rows0 = blockIdx.x * 32;
  for (int i = tid; i < 50*64; i += 256) vrl[i] = vr[i];
  for (int i = tid; i < 32*50; i += 256) wl[i] = wbins[(size_t)rows0*50 + i];
  __syncthreads();
  int wave = tid >> 6, lane = tid & 63;
  #pragma unroll
  for (int i = 0; i < 8; ++i) {
    int r = wave*8 + i;
    size_t idx = (size_t)rows0 + r;
    float acc = 0.f;
    #pragma unroll
    for (int j = 0; j < 50; ++j) acc += wl[r*50 + j] * vrl[j*64 + lane];
    int s = (int)(idx & 511); size_t bh = idx >> 9;
    int b = (int)(bh / 12), hh = (int)(bh % 12);
    u16* cp = ctx + ((size_t)(b*512 + s))*768 + hh*64 + lane;
    *cp = f2bf(bf2f(*cp) + acc);
  }
}

// ---------------------------------------------------------------- embeddings + LN
__global__ __launch_bounds__(256) void embed_ln(const int* __restrict__ ids,
    const float* __restrict__ we, const float* __restrict__ pe, const float* __restrict__ te,
    const float* __restrict__ g, const float* __restrict__ b,
    float* __restrict__ hF, u16* __restrict__ hB) {
  int row = blockIdx.x, tid = threadIdx.x;
  int s = row & 511;
  int id = ids[row];
  float x[3];
  #pragma unroll
  for (int j = 0; j < 3; ++j) {
    int d = tid + j*256;
    x[j] = we[(size_t)id*768 + d] + pe[(size_t)s*768 + d] + te[d];
  }
  __shared__ float red[4];
  float sm = x[0] + x[1] + x[2];
  #pragma unroll
  for (int o = 32; o; o >>= 1) sm += __shfl_xor(sm, o);
  if (!(tid & 63)) red[tid >> 6] = sm;
  __syncthreads();
  float mean = (red[0]+red[1]+red[2]+red[3]) * (1.f/768.f);
  __syncthreads();
  float q = 0.f;
  #pragma unroll
  for (int j = 0; j < 3; ++j) { float d = x[j] - mean; q += d*d; }
  #pragma unroll
  for (int o = 32; o; o >>= 1) q += __shfl_xor(q, o);
  if (!(tid & 63)) red[tid >> 6] = q;
  __syncthreads();
  float inv = rsqrtf((red[0]+red[1]+red[2]+red[3]) * (1.f/768.f) + 1e-12f);
  #pragma unroll
  for (int j = 0; j < 3; ++j) {
    int d = tid + j*256;
    float y = (x[j] - mean) * inv * g[d] + b[d];
    hF[(size_t)row*768 + d] = y;
    hB[(size_t)row*768 + d] = f2bf(y);
  }
}

// LN over (p0[+p1][+p2][+p3]) + bias + res
__global__ __launch_bounds__(256) void ln_fused(const float* __restrict__ p0,
    const float* __restrict__ p1, const float* __restrict__ p2, const float* __restrict__ p3,
    int np, const float* __restrict__ bias, const float* __restrict__ res,
    const float* __restrict__ g, const float* __restrict__ b,
    float* __restrict__ oF, u16* __restrict__ oB) {
  int row = blockIdx.x, tid = threadIdx.x;
  size_t base = (size_t)row * 768;
  float v[3];
  #pragma unroll
  for (int j = 0; j < 3; ++j) {
    int d = tid + j*256;
    float x = p0[base + d];
    if (np > 1) x += p1[base + d];
    if (np > 2) x += p2[base + d];
    if (np > 3) x += p3[base + d];
    v[j] = x + bias[d] + res[base + d];
  }
  __shared__ float red[4];
  float sm = v[0] + v[1] + v[2];
  #pragma unroll
  for (int o = 32; o; o >>= 1) sm += __shfl_xor(sm, o);
  if (!(tid & 63)) red[tid >> 6] = sm;
  __syncthreads();
  float mean = (red[0]+red[1]+red[2]+red[3]) * (1.f/768.f);
  __syncthreads();
  float q = 0.f;
  #pragma unroll
  for (int j = 0; j < 3; ++j) { float d = v[j] - mean; q += d*d; }
  #pragma unroll
  for (int o = 32; o; o >>= 1) q += __shfl_xor(q, o);
  if (!(tid & 63)) red[tid >> 6] = q;
  __syncthreads();
  float inv = rsqrtf((red[0]+red[1]+red[2]+red[3]) * (1.f/768.f) + 1e-12f);
  #pragma unroll
  for (int j = 0; j < 3; ++j) {
    int d = tid + j*256;
    float y = (v[j] - mean) * inv * g[d] + b[d];
    oF[base + d] = y;
    oB[base + d] = f2bf(y);
  }
}

// ---------------------------------------------------------------- tail
__global__ __launch_bounds__(256) void pooler_k(const float* __restrict__ h,
    const float* __restrict__ w, const float* __restrict__ bias, float* __restrict__ out) {
  int b = blockIdx.x, tid = threadIdx.x;
  __shared__ float hr[768];
  for (int i = tid; i < 768; i += 256) hr[i] = h[((size_t)b*512)*768 + i];
  __syncthreads();
  float a0 = 0.f, a1 = 0.f, a2 = 0.f;
  for (int kk = 0; kk < 768; ++kk) {
    float hv = hr[kk];
    const float* wr = w + (size_t)kk*768;
    a0 += hv * wr[tid]; a1 += hv * wr[tid+256]; a2 += hv * wr[tid+512];
  }
  out[(size_t)b*768 + tid]       = tanhf(a0 + bias[tid]);
  out[(size_t)b*768 + tid + 256] = tanhf(a1 + bias[tid+256]);
  out[(size_t)b*768 + tid + 512] = tanhf(a2 + bias[tid+512]);
}

__global__ __launch_bounds__(256) void copy_out(const float* __restrict__ in, float* __restrict__ out) {
  size_t i = ((size_t)blockIdx.x * 256 + threadIdx.x) * 4;
  *(float4*)(out + i) = *(const float4*)(in + i);
}

// ---------------------------------------------------------------- host
extern "C" void kernel_launch(void* const* d_in, const int* in_sizes, int n_in,
                              void* d_out, int out_size, void* d_ws, size_t ws_size,
                              hipStream_t stream) {
  const int*   ids   = (const int*)d_in[0];
  const int*   rel   = (const int*)d_in[1];
  const int*   amask = (const int*)d_in[2];
  const float* we    = (const float*)d_in[3];
  const float* pe    = (const float*)d_in[4];
  const float* te    = (const float*)d_in[5];
  const float* eg    = (const float*)d_in[6];
  const float* ebb   = (const float*)d_in[7];
  const float* Wq    = (const float*)d_in[8];
  const float* bq    = (const float*)d_in[9];
  const float* Wk    = (const float*)d_in[10];
  const float* bk    = (const float*)d_in[11];
  const float* Wv    = (const float*)d_in[12];
  const float* bv    = (const float*)d_in[13];
  const float* Wo    = (const float*)d_in[14];
  const float* bo    = (const float*)d_in[15];
  const float* g1    = (const float*)d_in[16];
  const float* b1    = (const float*)d_in[17];
  const float* Wi    = (const float*)d_in[18];
  const float* bi    = (const float*)d_in[19];
  const float* Wf    = (const float*)d_in[20];
  const float* bfp   = (const float*)d_in[21];
  const float* g2    = (const float*)d_in[22];
  const float* b2    = (const float*)d_in[23];
  const float* krel  = (const float*)d_in[24];
  const float* vrel  = (const float*)d_in[25];
  const float* pwp   = (const float*)d_in[26];
  const float* pbp   = (const float*)d_in[27];
  (void)in_sizes; (void)n_in; (void)out_size; (void)ws_size;

  char* ws = (char*)d_ws;
  size_t off = 0;
  auto take = [&](size_t bytes) { char* p = ws + off; off += (bytes + 255) & ~(size_t)255; return p; };
  u16*   wqkv = (u16*)take((size_t)2304*768*2);
  u16*   wo_l = (u16*)take((size_t)768*768*2);
  u16*   wi_l = (u16*)take((size_t)3072*768*2);
  u16*   wf_l = (u16*)take((size_t)768*3072*2);
  float* hF   = (float*)take((size_t)2048*768*4);
  u16*   hB   = (u16*)take((size_t)2048*768*2);
  float* atF  = (float*)take((size_t)2048*768*4);
  u16*   atB  = (u16*)take((size_t)2048*768*2);
  u16*   qB   = (u16*)take((size_t)2048*768*2);
  u16*   kB   = (u16*)take((size_t)2048*768*2);
  u16*   vB   = (u16*)take((size_t)2048*768*2);
  u16*   ctxB = (u16*)take((size_t)2048*768*2);
  // union: scF (25.2MB, layer-6 attention) aliases tmpF (split-K partials) — disjoint lifetimes
  char*  uni  = take((size_t)4*2048*768*4);
  float* tmpF = (float*)uni;
  u16*   scF  = (u16*)uni;
  u16*   ffB  = (u16*)take((size_t)2048*3072*2);
  u16*   prB  = (u16*)take((size_t)48*512*512*2);     // probs bf16 (layer 6)
  float* qrF  = (float*)take((size_t)24576*50*4);
  float* wbF  = (float*)take((size_t)24576*50*4);
  const size_t PSTRIDE = (size_t)2048*768;

  embed_ln<<<2048, 256, 0, stream>>>(ids, we, pe, te, eg, ebb, hF, hB);

  for (int l = 0; l < 12; ++l) {
    ConvP cp{Wq + (size_t)l*768*768, Wk + (size_t)l*768*768, Wv + (size_t)l*768*768,
             Wo + (size_t)l*768*768, Wi + (size_t)l*768*3072, Wf + (size_t)l*3072*768,
             wqkv, wo_l, wi_l, wf_l};
    conv_weights<<<6912, dim3(32,8), 0, stream>>>(cp);

    GP pq{}; pq.A = hB; pq.B = wqkv; pq.K = 768; pq.N = 2304;
    pq.bq = bq + l*768; pq.bk = bk + l*768; pq.bv = bv + l*768;
    pq.qO = qB; pq.kO = kB; pq.vO = vB;
    gemm_bt<128,128,8,0,1><<<dim3(18,16,1), 512, 0, stream>>>(pq);

    if (l == 6) {
      // RAT layer: materialized path (probs needed for relation bins)
      GP ps{}; ps.A = qB; ps.B = kB; ps.K = 64; ps.N = 512;
      ps.sA = 512*64; ps.sB = 512*64; ps.sOut = (long)512*512; ps.outB = scF;
      gemm_bt<128,128,8,4,1><<<dim3(4,4,48), 512, 0, stream>>>(ps);
      rat_qr<<<4800, 256, 0, stream>>>(qB, krel + 6*50*64, qrF);
      softmax_k<1><<<6144, 256, 0, stream>>>(scF, amask, prB, qrF, rel, wbF);
      GP pc{}; pc.A = prB; pc.B = vB; pc.K = 512; pc.N = 64;
      pc.sA = (long)512*512; pc.sB = 64*512; pc.outB = ctxB;
      gemm_bt<64,64,4,1,1><<<dim3(1,8,48), 256, 0, stream>>>(pc);
      rat_apply<<<768, 256, 0, stream>>>(wbF, vrel + 6*50*64, ctxB);
    } else {
      flash_attn<<<dim3(48,8), 256, 0, stream>>>(qB, kB, vB, amask, ctxB);
    }

    GP po{}; po.A = ctxB; po.B = wo_l; po.K = 768; po.N = 768; po.sOut = PSTRIDE;
    po.outF = tmpF;
    gemm_bt<64,128,4,2,2><<<dim3(6,32,2), 256, 0, stream>>>(po);
    ln_fused<<<2048, 256, 0, stream>>>(tmpF, tmpF + PSTRIDE, nullptr, nullptr, 2,
                                       bo + l*768, hF, g1 + l*768, b1 + l*768, atF, atB);

    GP pf1{}; pf1.A = atB; pf1.B = wi_l; pf1.K = 768; pf1.N = 3072;
    pf1.bias = bi + (size_t)l*3072; pf1.outB = ffB;
    gemm_bt<128,128,8,3,1><<<dim3(24,16,1), 512, 0, stream>>>(pf1);

    GP pf2{}; pf2.A = ffB; pf2.B = wf_l; pf2.K = 3072; pf2.N = 768; pf2.sOut = PSTRIDE;
    pf2.outF = tmpF;
    gemm_bt<64,128,4,2,4><<<dim3(6,32,4), 256, 0, stream>>>(pf2);
    ln_fused<<<2048, 256, 0, stream>>>(tmpF, tmpF + PSTRIDE, tmpF + 2*PSTRIDE, tmpF + 3*PSTRIDE, 4,
                                       bfp + l*768, atF, g2 + l*768, b2 + l*768, hF, hB);
  }

  copy_out<<<1536, 256, 0, stream>>>(hF, (float*)d_out);
  pooler_k<<<4, 256, 0, stream>>>(hF, pwp, pbp, (float*)d_out + (size_t)2048*768);
}